// Round 5
// baseline (496.475 us; speedup 1.0000x reference)
//
#include <hip/hip_runtime.h>
#include <cmath>

#define N_NODES   100000
#define N_EDGES   3200000
#define D_FEAT    512
#define HIDDEN    16
#define N_CLASSES 7

#define NCHUNK 625                   // scatter blocks; 625*5120 = 3.2M exactly, ~2.4 blocks/CU
#define CHUNK  5120
#define NBKT   1563                  // buckets of 64 nodes (dst>>6)
#define BCAP   2560                  // fixed bucket capacity; mean 2048, sigma 45 -> 11 sigma slack

typedef __attribute__((ext_vector_type(4))) float  f32x4;
typedef __attribute__((ext_vector_type(8))) short  bf16x8;

__device__ __forceinline__ short f2bf(float f) {
    union { float f; unsigned u; } v; v.f = f;
    unsigned r = v.u + 0x7fffu + ((v.u >> 16) & 1u);   // RNE
    return (short)(r >> 16);
}
__device__ __forceinline__ float bf2f(unsigned short s) {
    union { unsigned u; float f; } v; v.u = ((unsigned)s) << 16;
    return v.f;
}
__device__ __forceinline__ float bflo(unsigned u) {
    union { unsigned u; float f; } v; v.u = u << 16; return v.f;
}
__device__ __forceinline__ float bfhi(unsigned u) {
    union { unsigned u; float f; } v; v.u = u & 0xFFFF0000u; return v.f;
}

// ---- pass 1: per-chunk LDS hist -> reserve fixed-stride slices -> scatter --
// packed word = (dst & 63) << 24 | src    (src < 100000 < 2^24)
// bucket b's edges live at packed[b*BCAP .. b*BCAP + cnt[b])
__global__ __launch_bounds__(1024) void k_scatterD(const int* __restrict__ src,
                                                   const int* __restrict__ dst,
                                                   unsigned* __restrict__ cnt,
                                                   unsigned* __restrict__ packed) {
    __shared__ unsigned h[NBKT];
    int t = threadIdx.x, b = blockIdx.x;
    for (int i = t; i < NBKT; i += 1024) h[i] = 0u;
    __syncthreads();
    int base = b * CHUNK;
    // phase a: local histogram (CHUNK = 5*1024 exactly, no guard)
    #pragma unroll
    for (int k = 0; k < 5; ++k)
        atomicAdd(&h[((unsigned)dst[base + k * 1024 + t]) >> 6], 1u);
    __syncthreads();
    // phase b: reserve a contiguous slice of each bucket for this block
    for (int i = t; i < NBKT; i += 1024) {
        unsigned c = h[i];
        h[i] = c ? ((unsigned)i * BCAP + atomicAdd(&cnt[i], c)) : 0u;
    }
    __syncthreads();
    // phase c: scatter into reserved slices via LDS cursors
    #pragma unroll
    for (int k = 0; k < 5; ++k) {
        int e = base + k * 1024 + t;
        unsigned d = (unsigned)dst[e];
        unsigned pos = atomicAdd(&h[d >> 6], 1u);   // LDS atomic
        packed[pos] = ((d & 63u) << 24) | (unsigned)src[e];
    }
}

// -------- pass 2: per-bucket exact-dst sort -> deg, row_start, dinv, csr ---
__global__ __launch_bounds__(256) void k_bucket(const unsigned* __restrict__ packed,
                                                const unsigned* __restrict__ cnt,
                                                unsigned* __restrict__ deg,
                                                unsigned* __restrict__ row_start,
                                                float* __restrict__ dinv,
                                                int* __restrict__ csr_src) {
    __shared__ unsigned hh[4][64], sc[64], cur[64];
    int t = threadIdx.x, b = blockIdx.x;
    int w = t >> 6, l = t & 63;
    unsigned rs = (unsigned)b * BCAP;
    unsigned re = rs + cnt[b];
    hh[w][l] = 0u;
    __syncthreads();
    for (unsigned i = rs + t; i < re; i += 256)
        atomicAdd(&hh[w][packed[i] >> 24], 1u);    // per-wave sub-hist
    __syncthreads();
    unsigned total = 0u;
    if (t < 64) {
        total = hh[0][t] + hh[1][t] + hh[2][t] + hh[3][t];
        sc[t] = total;
    }
    __syncthreads();
    #pragma unroll
    for (int off = 1; off < 64; off <<= 1) {
        unsigned add = (t >= off && t < 64) ? sc[t - off] : 0u;
        __syncthreads();
        if (t < 64) sc[t] += add;
        __syncthreads();
    }
    if (t < 64) {
        unsigned excl = sc[t] - total;
        int node = b * 64 + t;
        if (node < N_NODES) {
            deg[node]       = total;
            row_start[node] = rs + excl;
            dinv[node]      = rsqrtf((float)(total + 1u));
        }
        cur[t] = rs + excl;
    }
    __syncthreads();
    for (unsigned i = rs + t; i < re; i += 256) {
        unsigned p = packed[i];
        unsigned pos = atomicAdd(&cur[p >> 24], 1u);     // LDS atomic
        csr_src[pos] = (int)(p & 0xFFFFFFu);
    }
}

// ------- GEMM1: h1p = bf16( dinv .* (x@W1) )  (bf16 MFMA, fp32 acc) --------
__global__ __launch_bounds__(256) void k_gemm1(const float* __restrict__ x,
                                               const float* __restrict__ w1,
                                               const float* __restrict__ dinv,
                                               unsigned short* __restrict__ h1p) {
    __shared__ __align__(16) short w1t[16][520];
    int tid = threadIdx.x;
    for (int idx = tid; idx < D_FEAT * HIDDEN; idx += 256) {
        int k = idx >> 4, n = idx & 15;
        w1t[n][k] = f2bf(w1[idx]);
    }
    __syncthreads();

    int lane = tid & 63, wid = tid >> 6;
    int m  = lane & 15;
    int kg = lane >> 4;

    bf16x8 bfrag[16];
    #pragma unroll
    for (int ks = 0; ks < 16; ++ks)
        bfrag[ks] = *(const bf16x8*)&w1t[m][ks * 32 + kg * 8];

    int tile = blockIdx.x * 4 + wid;
    if (tile >= (N_NODES / 16)) return;

    const f32x4* xr = (const f32x4*)(x + (size_t)(tile * 16 + m) * D_FEAT);
    f32x4 acc = {0.f, 0.f, 0.f, 0.f};
    #pragma unroll
    for (int ks = 0; ks < 16; ++ks) {
        f32x4 x0 = xr[ks * 8 + kg * 2];
        f32x4 x1 = xr[ks * 8 + kg * 2 + 1];
        bf16x8 a;
        a[0] = f2bf(x0[0]); a[1] = f2bf(x0[1]); a[2] = f2bf(x0[2]); a[3] = f2bf(x0[3]);
        a[4] = f2bf(x1[0]); a[5] = f2bf(x1[1]); a[6] = f2bf(x1[2]); a[7] = f2bf(x1[3]);
        acc = __builtin_amdgcn_mfma_f32_16x16x32_bf16(a, bfrag[ks], acc, 0, 0, 0);
    }
    // C layout: col = lane&15, row = (lane>>4)*4 + reg  [m89-verified]
    size_t base = (size_t)tile * 256;
    #pragma unroll
    for (int r = 0; r < 4; ++r) {
        int rr = kg * 4 + r;
        h1p[base + rr * 16 + m] = (unsigned short)f2bf(dinv[tile * 16 + rr] * acc[r]);
    }
}

// ------- gather layer 1 FUSED with layer 2, wide loads ---------------------
// lane = slot*2+half: lane loads 16B (half a h1p row) per edge; 32 edges/round.
// Butterfly reduce over parity groups; fused relu + W2 transform epilogue.
__global__ __launch_bounds__(256) void k_gather1(const int* __restrict__ csr_src,
                                                 const unsigned* __restrict__ row_start,
                                                 const unsigned* __restrict__ deg,
                                                 const unsigned short* __restrict__ h1p,
                                                 const float* __restrict__ dinv,
                                                 const float* __restrict__ w2,
                                                 const float* __restrict__ b1,
                                                 float* __restrict__ h2p) {
    __shared__ float w2s[16][8];
    __shared__ float b1s[16];
    int tid  = threadIdx.x;
    if (tid < 128) {
        int jj = tid >> 3, c = tid & 7;
        w2s[jj][c] = (c < N_CLASSES) ? w2[jj * N_CLASSES + c] : 0.f;
    }
    if (tid < 16) b1s[tid] = b1[tid];
    __syncthreads();

    int lane = tid & 63;
    int node = blockIdx.x * 4 + (tid >> 6);     // 25000*4 == N_NODES exactly
    int half = lane & 1;
    int slot = lane >> 1;                        // 0..31

    unsigned start = row_start[node];
    unsigned end   = start + deg[node];

    float acc[8] = {0,0,0,0,0,0,0,0};
    // self term (issued early; added on lanes 0,1 only)
    uint4 sv = *(const uint4*)(h1p + (size_t)node * 16 + half * 8);
    if (lane < 2) {
        acc[0] += bflo(sv.x); acc[1] += bfhi(sv.x);
        acc[2] += bflo(sv.y); acc[3] += bfhi(sv.y);
        acc[4] += bflo(sv.z); acc[5] += bfhi(sv.z);
        acc[6] += bflo(sv.w); acc[7] += bfhi(sv.w);
    }
    for (unsigned e0 = start; e0 < end; e0 += 32) {
        unsigned idx = e0 + (unsigned)slot;
        if (idx < end) {
            int s = csr_src[idx];
            uint4 rv = *(const uint4*)(h1p + (size_t)s * 16 + half * 8);
            acc[0] += bflo(rv.x); acc[1] += bfhi(rv.x);
            acc[2] += bflo(rv.y); acc[3] += bfhi(rv.y);
            acc[4] += bflo(rv.z); acc[5] += bfhi(rv.z);
            acc[6] += bflo(rv.w); acc[7] += bfhi(rv.w);
        }
    }
    // butterfly over same-parity lanes (masks 2,4,8,16,32)
    #pragma unroll
    for (int mk = 2; mk <= 32; mk <<= 1) {
        #pragma unroll
        for (int k = 0; k < 8; ++k) acc[k] += __shfl_xor(acc[k], mk);
    }
    float oth[8];
    #pragma unroll
    for (int k = 0; k < 8; ++k) oth[k] = __shfl_xor(acc[k], 1);

    float di = dinv[node];
    float h[16];
    #pragma unroll
    for (int k = 0; k < 8; ++k) {
        float glo = half ? oth[k] : acc[k];     // feats k
        float ghi = half ? acc[k] : oth[k];     // feats 8+k
        h[k]     = fmaxf(fmaf(di, glo, b1s[k]),     0.f);
        h[k + 8] = fmaxf(fmaf(di, ghi, b1s[k + 8]), 0.f);
    }
    int c = lane & 7;
    float o = 0.f;
    #pragma unroll
    for (int j = 0; j < 16; ++j) o = fmaf(h[j], w2s[j][c], o);
    if (lane < 8)
        h2p[(size_t)node * 8 + c] = (c < N_CLASSES) ? di * o : 0.f;
}

// ------- gather layer 2 + bias + log_softmax fused, wide loads -------------
// lane = slot*2+half: lane loads 16B (half a h2p row) per edge; 32 edges/round.
__global__ __launch_bounds__(256) void k_gather2(const int* __restrict__ csr_src,
                                                 const unsigned* __restrict__ row_start,
                                                 const unsigned* __restrict__ deg,
                                                 const float* __restrict__ dinv,
                                                 const float* __restrict__ h2p,
                                                 const float* __restrict__ b2,
                                                 float* __restrict__ out) {
    int tid  = threadIdx.x;
    int lane = tid & 63;
    int node = blockIdx.x * 4 + (tid >> 6);
    int half = lane & 1;
    int slot = lane >> 1;

    unsigned start = row_start[node];
    unsigned end   = start + deg[node];

    float acc[4] = {0, 0, 0, 0};
    f32x4 sv = *(const f32x4*)(h2p + (size_t)node * 8 + half * 4);
    if (lane < 2) { acc[0] += sv[0]; acc[1] += sv[1]; acc[2] += sv[2]; acc[3] += sv[3]; }
    for (unsigned e0 = start; e0 < end; e0 += 32) {
        unsigned idx = e0 + (unsigned)slot;
        if (idx < end) {
            int s = csr_src[idx];
            f32x4 rv = *(const f32x4*)(h2p + (size_t)s * 8 + half * 4);
            acc[0] += rv[0]; acc[1] += rv[1]; acc[2] += rv[2]; acc[3] += rv[3];
        }
    }
    #pragma unroll
    for (int mk = 2; mk <= 32; mk <<= 1) {
        #pragma unroll
        for (int k = 0; k < 4; ++k) acc[k] += __shfl_xor(acc[k], mk);
    }
    float oth[4];
    #pragma unroll
    for (int k = 0; k < 4; ++k) oth[k] = __shfl_xor(acc[k], 1);

    float l[8];
    #pragma unroll
    for (int k = 0; k < 4; ++k) {
        l[k]     = half ? oth[k] : acc[k];      // classes 0..3
        l[k + 4] = half ? acc[k] : oth[k];      // classes 4..7
    }
    float di = dinv[node];
    float lg[N_CLASSES];
    float mx = -1e30f;
    #pragma unroll
    for (int cc = 0; cc < N_CLASSES; ++cc) {
        lg[cc] = fmaf(di, l[cc], b2[cc]);
        mx = fmaxf(mx, lg[cc]);
    }
    float sum = 0.f;
    #pragma unroll
    for (int cc = 0; cc < N_CLASSES; ++cc) sum += __expf(lg[cc] - mx);
    float lse = mx + __logf(sum);
    if (lane < N_CLASSES) {
        float v = lg[0];
        #pragma unroll
        for (int cc = 1; cc < N_CLASSES; ++cc) if (lane == cc) v = lg[cc];
        out[(size_t)node * N_CLASSES + lane] = v - lse;
    }
}

extern "C" void kernel_launch(void* const* d_in, const int* in_sizes, int n_in,
                              void* d_out, int out_size, void* d_ws, size_t ws_size,
                              hipStream_t stream) {
    const float* x  = (const float*)d_in[0];
    const int*   ei = (const int*)d_in[1];
    const float* w1 = (const float*)d_in[2];
    const float* b1 = (const float*)d_in[3];
    const float* w2 = (const float*)d_in[4];
    const float* b2 = (const float*)d_in[5];
    float* out = (float*)d_out;

    const int* src = ei;
    const int* dst = ei + N_EDGES;

    // workspace carve (u32 units), ~40 MB
    unsigned* w32            = (unsigned*)d_ws;
    float*    dinv           = (float*)(w32 + 0);                   // 102,400
    unsigned short* h1p      = (unsigned short*)(w32 + 102400);     // 1.6M ushort = 800,000 u32
    float*    h2p            = (float*)(w32 + 902400);              //   800,000
    unsigned* deg            = w32 + 1702400;                       // 102,400
    unsigned* row_start      = w32 + 1804800;                       // 102,400
    unsigned* cnt            = w32 + 1907200;                       // 2,048
    unsigned* packed         = w32 + 1909248;                       // 4,001,280 (NBKT*BCAP)
    int*      csr_src        = (int*)(w32 + 5910528);               // 4,001,280

    const int GB = (N_NODES / 16 + 3) / 4;             // 1563 gemm blocks

    hipMemsetAsync(cnt, 0, NBKT * sizeof(unsigned), stream);
    k_scatterD<<<NCHUNK, 1024, 0, stream>>>(src, dst, cnt, packed);
    k_bucket  <<<NBKT,   256,  0, stream>>>(packed, cnt, deg, row_start, dinv, csr_src);
    k_gemm1   <<<GB,     256,  0, stream>>>(x, w1, dinv, h1p);
    k_gather1 <<<25000,  256,  0, stream>>>(csr_src, row_start, deg, h1p, dinv, w2, b1, h2p);
    k_gather2 <<<25000,  256,  0, stream>>>(csr_src, row_start, deg, dinv, h2p, b2, out);
}

// Round 6
// 478.409 us; speedup vs baseline: 1.0378x; 1.0378x over previous
//
#include <hip/hip_runtime.h>
#include <cmath>

#define N_NODES   100000
#define N_EDGES   3200000
#define D_FEAT    512
#define HIDDEN    16
#define N_CLASSES 7

#define NCHUNK 625                   // scatter blocks; 625*5120 = 3.2M exactly
#define CHUNK  5120
#define NBKT   1563                  // buckets of 64 nodes (dst>>6)
#define BCAP   2560                  // fixed bucket capacity; mean 2048, sigma 45 -> 11 sigma slack
#define GEMMB  391                   // gemm blocks in fused K1: 391*16 tiles >= 6250

typedef __attribute__((ext_vector_type(4))) float  f32x4;
typedef __attribute__((ext_vector_type(8))) short  bf16x8;

__device__ __forceinline__ short f2bf(float f) {
    union { float f; unsigned u; } v; v.f = f;
    unsigned r = v.u + 0x7fffu + ((v.u >> 16) & 1u);   // RNE
    return (short)(r >> 16);
}
__device__ __forceinline__ float bf2f(unsigned short s) {
    union { unsigned u; float f; } v; v.u = ((unsigned)s) << 16;
    return v.f;
}
__device__ __forceinline__ float bflo(unsigned u) {
    union { unsigned u; float f; } v; v.u = u << 16; return v.f;
}
__device__ __forceinline__ float bfhi(unsigned u) {
    union { unsigned u; float f; } v; v.u = u & 0xFFFF0000u; return v.f;
}

// ==== K1: heterogeneous fusion =============================================
// blocks [0, NCHUNK)           : edge scatter into fixed-stride buckets
// blocks [NCHUNK, NCHUNK+GEMMB): graw = x @ W1 (f32 out, no dinv scale)
// The two phases are data-independent; scatter is latency/atomic-bound while
// gemm is BW-bound (205 MB of x) -> they overlap instead of serializing.
__global__ __launch_bounds__(1024) void k_fused1(const int* __restrict__ src,
                                                 const int* __restrict__ dst,
                                                 unsigned* __restrict__ cnt,
                                                 unsigned* __restrict__ packed,
                                                 const float* __restrict__ x,
                                                 const float* __restrict__ w1,
                                                 float* __restrict__ graw) {
    __shared__ __align__(16) short w1t[16][520];     // gemm path (16.6 KB)
    __shared__ unsigned h[NBKT];                     // scatter path (6.25 KB)
    int t = threadIdx.x;

    if (blockIdx.x < NCHUNK) {
        // ---------------- scatter path ----------------
        int b = blockIdx.x;
        for (int i = t; i < NBKT; i += 1024) h[i] = 0u;
        __syncthreads();
        int base = b * CHUNK;
        #pragma unroll
        for (int k = 0; k < 5; ++k)
            atomicAdd(&h[((unsigned)dst[base + k * 1024 + t]) >> 6], 1u);
        __syncthreads();
        for (int i = t; i < NBKT; i += 1024) {
            unsigned c = h[i];
            h[i] = c ? ((unsigned)i * BCAP + atomicAdd(&cnt[i], c)) : 0u;
        }
        __syncthreads();
        #pragma unroll
        for (int k = 0; k < 5; ++k) {
            int e = base + k * 1024 + t;
            unsigned d = (unsigned)dst[e];
            unsigned pos = atomicAdd(&h[d >> 6], 1u);   // LDS atomic
            packed[pos] = ((d & 63u) << 24) | (unsigned)src[e];
        }
    } else {
        // ---------------- gemm path (16 waves = 16 row-tiles) ----------------
        for (int idx = t; idx < D_FEAT * HIDDEN; idx += 1024) {
            int k = idx >> 4, n = idx & 15;
            w1t[n][k] = f2bf(w1[idx]);
        }
        __syncthreads();
        int lane = t & 63, wid = t >> 6;          // wid 0..15
        int m  = lane & 15;
        int kg = lane >> 4;
        int tile = (blockIdx.x - NCHUNK) * 16 + wid;
        if (tile >= (N_NODES / 16)) return;

        const f32x4* xr = (const f32x4*)(x + (size_t)(tile * 16 + m) * D_FEAT);
        f32x4 acc = {0.f, 0.f, 0.f, 0.f};
        #pragma unroll
        for (int ks = 0; ks < 16; ++ks) {
            f32x4 x0 = xr[ks * 8 + kg * 2];
            f32x4 x1 = xr[ks * 8 + kg * 2 + 1];
            bf16x8 a;
            a[0] = f2bf(x0[0]); a[1] = f2bf(x0[1]); a[2] = f2bf(x0[2]); a[3] = f2bf(x0[3]);
            a[4] = f2bf(x1[0]); a[5] = f2bf(x1[1]); a[6] = f2bf(x1[2]); a[7] = f2bf(x1[3]);
            bf16x8 bb = *(const bf16x8*)&w1t[m][ks * 32 + kg * 8];
            acc = __builtin_amdgcn_mfma_f32_16x16x32_bf16(a, bb, acc, 0, 0, 0);
        }
        // C layout: col = lane&15, row = (lane>>4)*4 + reg  [m89-verified]
        size_t base = (size_t)tile * 256;
        #pragma unroll
        for (int r = 0; r < 4; ++r)
            graw[base + (kg * 4 + r) * 16 + m] = acc[r];
    }
}

// ==== K2: per-bucket exact-dst sort + dinv + h1p = bf16(dinv*graw) =========
__global__ __launch_bounds__(256) void k_bucket(const unsigned* __restrict__ packed,
                                                const unsigned* __restrict__ cnt,
                                                const float* __restrict__ graw,
                                                unsigned* __restrict__ deg,
                                                unsigned* __restrict__ row_start,
                                                float* __restrict__ dinv,
                                                int* __restrict__ csr_src,
                                                unsigned short* __restrict__ h1p) {
    __shared__ unsigned hh[4][64], sc[64], cur[64];
    __shared__ float dls[64];
    int t = threadIdx.x, b = blockIdx.x;
    int w = t >> 6, l = t & 63;
    unsigned rs = (unsigned)b * BCAP;
    unsigned re = rs + cnt[b];
    hh[w][l] = 0u;
    __syncthreads();
    for (unsigned i = rs + t; i < re; i += 256)
        atomicAdd(&hh[w][packed[i] >> 24], 1u);    // per-wave sub-hist
    __syncthreads();
    unsigned total = 0u;
    if (t < 64) {
        total = hh[0][t] + hh[1][t] + hh[2][t] + hh[3][t];
        sc[t] = total;
    }
    __syncthreads();
    #pragma unroll
    for (int off = 1; off < 64; off <<= 1) {
        unsigned add = (t >= off && t < 64) ? sc[t - off] : 0u;
        __syncthreads();
        if (t < 64) sc[t] += add;
        __syncthreads();
    }
    if (t < 64) {
        unsigned excl = sc[t] - total;
        int node = b * 64 + t;
        float di = rsqrtf((float)(total + 1u));
        dls[t] = di;
        if (node < N_NODES) {
            deg[node]       = total;
            row_start[node] = rs + excl;
            dinv[node]      = di;
        }
        cur[t] = rs + excl;
    }
    __syncthreads();
    // scale this bucket's 64 graw rows into bf16 h1p (identical numerics to
    // the old in-gemm epilogue: f2bf(dinv * acc))
    #pragma unroll
    for (int k = 0; k < 4; ++k) {
        int i = t + k * 256;                 // 0..1023 = 64 nodes x 16 feats
        int node = b * 64 + (i >> 4);
        if (node < N_NODES)
            h1p[(size_t)b * 1024 + i] =
                (unsigned short)f2bf(dls[i >> 4] * graw[(size_t)b * 1024 + i]);
    }
    for (unsigned i = rs + t; i < re; i += 256) {
        unsigned p = packed[i];
        unsigned pos = atomicAdd(&cur[p >> 24], 1u);     // LDS atomic
        csr_src[pos] = (int)(p & 0xFFFFFFu);
    }
}

// ------- gather layer 1 FUSED with layer 2, wide loads ---------------------
// lane = slot*2+half: lane loads 16B (half a h1p row) per edge; 32 edges/round.
__global__ __launch_bounds__(256) void k_gather1(const int* __restrict__ csr_src,
                                                 const unsigned* __restrict__ row_start,
                                                 const unsigned* __restrict__ deg,
                                                 const unsigned short* __restrict__ h1p,
                                                 const float* __restrict__ dinv,
                                                 const float* __restrict__ w2,
                                                 const float* __restrict__ b1,
                                                 float* __restrict__ h2p) {
    __shared__ float w2s[16][8];
    __shared__ float b1s[16];
    int tid  = threadIdx.x;
    if (tid < 128) {
        int jj = tid >> 3, c = tid & 7;
        w2s[jj][c] = (c < N_CLASSES) ? w2[jj * N_CLASSES + c] : 0.f;
    }
    if (tid < 16) b1s[tid] = b1[tid];
    __syncthreads();

    int lane = tid & 63;
    int node = blockIdx.x * 4 + (tid >> 6);     // 25000*4 == N_NODES exactly
    int half = lane & 1;
    int slot = lane >> 1;                        // 0..31

    unsigned start = row_start[node];
    unsigned end   = start + deg[node];

    float acc[8] = {0,0,0,0,0,0,0,0};
    uint4 sv = *(const uint4*)(h1p + (size_t)node * 16 + half * 8);
    if (lane < 2) {
        acc[0] += bflo(sv.x); acc[1] += bfhi(sv.x);
        acc[2] += bflo(sv.y); acc[3] += bfhi(sv.y);
        acc[4] += bflo(sv.z); acc[5] += bfhi(sv.z);
        acc[6] += bflo(sv.w); acc[7] += bfhi(sv.w);
    }
    for (unsigned e0 = start; e0 < end; e0 += 32) {
        unsigned idx = e0 + (unsigned)slot;
        if (idx < end) {
            int s = csr_src[idx];
            uint4 rv = *(const uint4*)(h1p + (size_t)s * 16 + half * 8);
            acc[0] += bflo(rv.x); acc[1] += bfhi(rv.x);
            acc[2] += bflo(rv.y); acc[3] += bfhi(rv.y);
            acc[4] += bflo(rv.z); acc[5] += bfhi(rv.z);
            acc[6] += bflo(rv.w); acc[7] += bfhi(rv.w);
        }
    }
    #pragma unroll
    for (int mk = 2; mk <= 32; mk <<= 1) {
        #pragma unroll
        for (int k = 0; k < 8; ++k) acc[k] += __shfl_xor(acc[k], mk);
    }
    float oth[8];
    #pragma unroll
    for (int k = 0; k < 8; ++k) oth[k] = __shfl_xor(acc[k], 1);

    float di = dinv[node];
    float h[16];
    #pragma unroll
    for (int k = 0; k < 8; ++k) {
        float glo = half ? oth[k] : acc[k];     // feats k
        float ghi = half ? acc[k] : oth[k];     // feats 8+k
        h[k]     = fmaxf(fmaf(di, glo, b1s[k]),     0.f);
        h[k + 8] = fmaxf(fmaf(di, ghi, b1s[k + 8]), 0.f);
    }
    int c = lane & 7;
    float o = 0.f;
    #pragma unroll
    for (int j = 0; j < 16; ++j) o = fmaf(h[j], w2s[j][c], o);
    if (lane < 8)
        h2p[(size_t)node * 8 + c] = (c < N_CLASSES) ? di * o : 0.f;
}

// ------- gather layer 2 + bias + log_softmax fused, wide loads -------------
__global__ __launch_bounds__(256) void k_gather2(const int* __restrict__ csr_src,
                                                 const unsigned* __restrict__ row_start,
                                                 const unsigned* __restrict__ deg,
                                                 const float* __restrict__ dinv,
                                                 const float* __restrict__ h2p,
                                                 const float* __restrict__ b2,
                                                 float* __restrict__ out) {
    int tid  = threadIdx.x;
    int lane = tid & 63;
    int node = blockIdx.x * 4 + (tid >> 6);
    int half = lane & 1;
    int slot = lane >> 1;

    unsigned start = row_start[node];
    unsigned end   = start + deg[node];

    float acc[4] = {0, 0, 0, 0};
    f32x4 sv = *(const f32x4*)(h2p + (size_t)node * 8 + half * 4);
    if (lane < 2) { acc[0] += sv[0]; acc[1] += sv[1]; acc[2] += sv[2]; acc[3] += sv[3]; }
    for (unsigned e0 = start; e0 < end; e0 += 32) {
        unsigned idx = e0 + (unsigned)slot;
        if (idx < end) {
            int s = csr_src[idx];
            f32x4 rv = *(const f32x4*)(h2p + (size_t)s * 8 + half * 4);
            acc[0] += rv[0]; acc[1] += rv[1]; acc[2] += rv[2]; acc[3] += rv[3];
        }
    }
    #pragma unroll
    for (int mk = 2; mk <= 32; mk <<= 1) {
        #pragma unroll
        for (int k = 0; k < 4; ++k) acc[k] += __shfl_xor(acc[k], mk);
    }
    float oth[4];
    #pragma unroll
    for (int k = 0; k < 4; ++k) oth[k] = __shfl_xor(acc[k], 1);

    float l[8];
    #pragma unroll
    for (int k = 0; k < 4; ++k) {
        l[k]     = half ? oth[k] : acc[k];      // classes 0..3
        l[k + 4] = half ? acc[k] : oth[k];      // classes 4..7
    }
    float di = dinv[node];
    float lg[N_CLASSES];
    float mx = -1e30f;
    #pragma unroll
    for (int cc = 0; cc < N_CLASSES; ++cc) {
        lg[cc] = fmaf(di, l[cc], b2[cc]);
        mx = fmaxf(mx, lg[cc]);
    }
    float sum = 0.f;
    #pragma unroll
    for (int cc = 0; cc < N_CLASSES; ++cc) sum += __expf(lg[cc] - mx);
    float lse = mx + __logf(sum);
    if (lane < N_CLASSES) {
        float v = lg[0];
        #pragma unroll
        for (int cc = 1; cc < N_CLASSES; ++cc) if (lane == cc) v = lg[cc];
        out[(size_t)node * N_CLASSES + lane] = v - lse;
    }
}

extern "C" void kernel_launch(void* const* d_in, const int* in_sizes, int n_in,
                              void* d_out, int out_size, void* d_ws, size_t ws_size,
                              hipStream_t stream) {
    const float* x  = (const float*)d_in[0];
    const int*   ei = (const int*)d_in[1];
    const float* w1 = (const float*)d_in[2];
    const float* b1 = (const float*)d_in[3];
    const float* w2 = (const float*)d_in[4];
    const float* b2 = (const float*)d_in[5];
    float* out = (float*)d_out;

    const int* src = ei;
    const int* dst = ei + N_EDGES;

    // workspace carve (u32 units), ~46 MB
    unsigned* w32            = (unsigned*)d_ws;
    float*    dinv           = (float*)(w32 + 0);                   // 102,400
    unsigned short* h1p      = (unsigned short*)(w32 + 102400);     // 1.6M ushort = 800,000 u32
    float*    h2p            = (float*)(w32 + 902400);              //   800,000
    unsigned* deg            = w32 + 1702400;                       // 102,400
    unsigned* row_start      = w32 + 1804800;                       // 102,400
    unsigned* cnt            = w32 + 1907200;                       // 2,048
    float*    graw           = (float*)(w32 + 1909248);             // 1,600,000
    unsigned* packed         = w32 + 3509248;                       // 4,001,280 (NBKT*BCAP)
    int*      csr_src        = (int*)(w32 + 7510528);               // 4,001,280

    hipMemsetAsync(cnt, 0, NBKT * sizeof(unsigned), stream);
    k_fused1 <<<NCHUNK + GEMMB, 1024, 0, stream>>>(src, dst, cnt, packed, x, w1, graw);
    k_bucket <<<NBKT,  256, 0, stream>>>(packed, cnt, graw, deg, row_start, dinv, csr_src, h1p);
    k_gather1<<<25000, 256, 0, stream>>>(csr_src, row_start, deg, h1p, dinv, w2, b1, h2p);
    k_gather2<<<25000, 256, 0, stream>>>(csr_src, row_start, deg, dinv, h2p, b2, out);
}

// Round 8
// 439.273 us; speedup vs baseline: 1.1302x; 1.0891x over previous
//
#include <hip/hip_runtime.h>
#include <cmath>

#define N_NODES   100000
#define N_EDGES   3200000
#define D_FEAT    512
#define HIDDEN    16
#define N_CLASSES 7

#define SBLK   160                   // scatter blocks; 160*20000 = 3.2M exactly
#define SCH    20000                 // edges per scatter block
#define NBKT   1563                  // buckets of 64 nodes (dst>>6)
#define BCAP   2560                  // fixed bucket capacity; mean 2048, sigma 45 -> 11 sigma slack
#define GEMMB  391                   // gemm blocks in fused K1: 391*16 tiles >= 6250

typedef __attribute__((ext_vector_type(4))) float  f32x4;
typedef __attribute__((ext_vector_type(8))) short  bf16x8;

__device__ __forceinline__ short f2bf(float f) {
    union { float f; unsigned u; } v; v.f = f;
    unsigned r = v.u + 0x7fffu + ((v.u >> 16) & 1u);   // RNE
    return (short)(r >> 16);
}
__device__ __forceinline__ float bf2f(unsigned short s) {
    union { unsigned u; float f; } v; v.u = ((unsigned)s) << 16;
    return v.f;
}
__device__ __forceinline__ float bflo(unsigned u) {
    union { unsigned u; float f; } v; v.u = u << 16; return v.f;
}
__device__ __forceinline__ float bfhi(unsigned u) {
    union { unsigned u; float f; } v; v.u = u & 0xFFFF0000u; return v.f;
}

// ==== K1: heterogeneous fusion =============================================
// blocks [0, SBLK)           : LDS counting-sort scatter into fixed buckets
// blocks [SBLK, SBLK+GEMMB)  : graw = x @ W1 (f32 out, no dinv scale)
// Scatter is latency/atomic-bound, gemm is BW-bound -> chip-level overlap.
// Scatter per block: hist -> block scan -> LDS sort -> contiguous run
// copy-out (avg run 12.8 edges => ~1 cache line vs 4B scattered writes).
__global__ __launch_bounds__(1024) void k_fused1(const int* __restrict__ src,
                                                 const int* __restrict__ dst,
                                                 unsigned* __restrict__ cnt,
                                                 unsigned* __restrict__ packed,
                                                 const float* __restrict__ x,
                                                 const float* __restrict__ w1,
                                                 float* __restrict__ graw) {
    // LDS union: scatter path needs hist/lstart/gbase/buf = 98.8 KB;
    // gemm path needs w1t = 16.6 KB. Single array, aliased per path.
    __shared__ __align__(16) unsigned smem[4691 + SCH];   // 98,764 B
    int t = threadIdx.x;

    if (blockIdx.x < SBLK) {
        // ---------------- scatter path ----------------
        unsigned* hist   = smem;            // [NBKT]  counts, then cursors
        unsigned* lstart = smem + 1563;     // [NBKT+1] local exclusive scan
        unsigned* gbase  = smem + 3127;     // [NBKT]  global run base
        unsigned* buf    = smem + 4691;     // [SCH]   sorted edges
        int b = blockIdx.x;
        int ebase = b * SCH;

        for (int i = t; i < NBKT; i += 1024) hist[i] = 0u;
        __syncthreads();
        // phase 1: histogram
        for (int k = 0; k < 20; ++k) {
            int idx = k * 1024 + t;
            if (idx < SCH) atomicAdd(&hist[((unsigned)dst[ebase + idx]) >> 6], 1u);
        }
        __syncthreads();
        // phase 2: exclusive scan of hist -> lstart (2 bins/thread + H-S scan)
        {
            unsigned* sc = buf;             // alias scratch
            int i0 = t * 2;
            unsigned a0 = (i0     < NBKT) ? hist[i0]     : 0u;
            unsigned a1 = (i0 + 1 < NBKT) ? hist[i0 + 1] : 0u;
            unsigned s  = a0 + a1;
            sc[t] = s; __syncthreads();
            #pragma unroll
            for (int off = 1; off < 1024; off <<= 1) {
                unsigned add = (t >= off) ? sc[t - off] : 0u;
                __syncthreads();
                sc[t] += add;
                __syncthreads();
            }
            unsigned excl = sc[t] - s;
            if (i0     < NBKT) lstart[i0]     = excl;
            if (i0 + 1 < NBKT) lstart[i0 + 1] = excl + a0;
            if (t == 0) lstart[NBKT] = (unsigned)SCH;
        }
        __syncthreads();
        // phase 3: reserve global runs; hist becomes LDS cursor
        for (int i = t; i < NBKT; i += 1024) {
            unsigned c = hist[i];
            gbase[i] = c ? ((unsigned)i * BCAP + atomicAdd(&cnt[i], c)) : 0u;
        }
        __syncthreads();
        for (int i = t; i < NBKT; i += 1024) hist[i] = lstart[i];
        __syncthreads();
        // phase 4: scatter into LDS buf (sorted by bucket)
        for (int k = 0; k < 20; ++k) {
            int idx = k * 1024 + t;
            if (idx < SCH) {
                int e = ebase + idx;
                unsigned d = (unsigned)dst[e];
                unsigned pos = atomicAdd(&hist[d >> 6], 1u);   // LDS atomic
                buf[pos] = ((d & 63u) << 24) | (unsigned)src[e];
            }
        }
        __syncthreads();
        // phase 5: contiguous run copy-out (wave per bucket, stride 16)
        int w = t >> 6, lane = t & 63;
        for (int i = w; i < NBKT; i += 16) {
            unsigned ls = lstart[i];
            unsigned c  = lstart[i + 1] - ls;
            unsigned gb = gbase[i];
            for (unsigned j = lane; j < c; j += 64)
                packed[gb + j] = buf[ls + j];
        }
    } else {
        // ---------------- gemm path (16 waves = 16 row-tiles) ----------------
        short (*w1t)[520] = (short(*)[520])smem;
        for (int idx = t; idx < D_FEAT * HIDDEN; idx += 1024) {
            int k = idx >> 4, n = idx & 15;
            w1t[n][k] = f2bf(w1[idx]);
        }
        __syncthreads();
        int lane = t & 63, wid = t >> 6;          // wid 0..15
        int m  = lane & 15;
        int kg = lane >> 4;
        int tile = (blockIdx.x - SBLK) * 16 + wid;
        if (tile >= (N_NODES / 16)) return;

        const f32x4* xr = (const f32x4*)(x + (size_t)(tile * 16 + m) * D_FEAT);
        f32x4 acc = {0.f, 0.f, 0.f, 0.f};
        #pragma unroll
        for (int ks = 0; ks < 16; ++ks) {
            f32x4 x0 = xr[ks * 8 + kg * 2];
            f32x4 x1 = xr[ks * 8 + kg * 2 + 1];
            bf16x8 a;
            a[0] = f2bf(x0[0]); a[1] = f2bf(x0[1]); a[2] = f2bf(x0[2]); a[3] = f2bf(x0[3]);
            a[4] = f2bf(x1[0]); a[5] = f2bf(x1[1]); a[6] = f2bf(x1[2]); a[7] = f2bf(x1[3]);
            bf16x8 bb = *(const bf16x8*)&w1t[m][ks * 32 + kg * 8];
            acc = __builtin_amdgcn_mfma_f32_16x16x32_bf16(a, bb, acc, 0, 0, 0);
        }
        // C layout: col = lane&15, row = (lane>>4)*4 + reg  [m89-verified]
        size_t base = (size_t)tile * 256;
        #pragma unroll
        for (int r = 0; r < 4; ++r)
            graw[base + (kg * 4 + r) * 16 + m] = acc[r];
    }
}

// ==== K2: per-bucket exact-dst sort + dinv + h1p = bf16(dinv*graw) =========
__global__ __launch_bounds__(256) void k_bucket(const unsigned* __restrict__ packed,
                                                const unsigned* __restrict__ cnt,
                                                const float* __restrict__ graw,
                                                unsigned* __restrict__ deg,
                                                unsigned* __restrict__ row_start,
                                                float* __restrict__ dinv,
                                                int* __restrict__ csr_src,
                                                unsigned short* __restrict__ h1p) {
    __shared__ unsigned hh[4][64], sc[64], cur[64];
    __shared__ float dls[64];
    int t = threadIdx.x, b = blockIdx.x;
    int w = t >> 6, l = t & 63;
    unsigned rs = (unsigned)b * BCAP;
    unsigned re = rs + cnt[b];
    hh[w][l] = 0u;
    __syncthreads();
    for (unsigned i = rs + t; i < re; i += 256)
        atomicAdd(&hh[w][packed[i] >> 24], 1u);    // per-wave sub-hist
    __syncthreads();
    unsigned total = 0u;
    if (t < 64) {
        total = hh[0][t] + hh[1][t] + hh[2][t] + hh[3][t];
        sc[t] = total;
    }
    __syncthreads();
    #pragma unroll
    for (int off = 1; off < 64; off <<= 1) {
        unsigned add = (t >= off && t < 64) ? sc[t - off] : 0u;
        __syncthreads();
        if (t < 64) sc[t] += add;
        __syncthreads();
    }
    if (t < 64) {
        unsigned excl = sc[t] - total;
        int node = b * 64 + t;
        float di = rsqrtf((float)(total + 1u));
        dls[t] = di;
        if (node < N_NODES) {
            deg[node]       = total;
            row_start[node] = rs + excl;
            dinv[node]      = di;
        }
        cur[t] = rs + excl;
    }
    __syncthreads();
    // scale this bucket's 64 graw rows into bf16 h1p (identical numerics to
    // the old in-gemm epilogue: f2bf(dinv * acc))
    #pragma unroll
    for (int k = 0; k < 4; ++k) {
        int i = t + k * 256;                 // 0..1023 = 64 nodes x 16 feats
        int node = b * 64 + (i >> 4);
        if (node < N_NODES)
            h1p[(size_t)b * 1024 + i] =
                (unsigned short)f2bf(dls[i >> 4] * graw[(size_t)b * 1024 + i]);
    }
    for (unsigned i = rs + t; i < re; i += 256) {
        unsigned p = packed[i];
        unsigned pos = atomicAdd(&cur[p >> 24], 1u);     // LDS atomic
        csr_src[pos] = (int)(p & 0xFFFFFFu);
    }
}

// ------- gather layer 1 FUSED with layer 2, wide loads ---------------------
// lane = slot*2+half: lane loads 16B (half a h1p row) per edge; 32 edges/round.
__global__ __launch_bounds__(256) void k_gather1(const int* __restrict__ csr_src,
                                                 const unsigned* __restrict__ row_start,
                                                 const unsigned* __restrict__ deg,
                                                 const unsigned short* __restrict__ h1p,
                                                 const float* __restrict__ dinv,
                                                 const float* __restrict__ w2,
                                                 const float* __restrict__ b1,
                                                 float* __restrict__ h2p) {
    __shared__ float w2s[16][8];
    __shared__ float b1s[16];
    int tid  = threadIdx.x;
    if (tid < 128) {
        int jj = tid >> 3, c = tid & 7;
        w2s[jj][c] = (c < N_CLASSES) ? w2[jj * N_CLASSES + c] : 0.f;
    }
    if (tid < 16) b1s[tid] = b1[tid];
    __syncthreads();

    int lane = tid & 63;
    int node = blockIdx.x * 4 + (tid >> 6);     // 25000*4 == N_NODES exactly
    int half = lane & 1;
    int slot = lane >> 1;                        // 0..31

    unsigned start = row_start[node];
    unsigned end   = start + deg[node];

    float acc[8] = {0,0,0,0,0,0,0,0};
    uint4 sv = *(const uint4*)(h1p + (size_t)node * 16 + half * 8);
    if (lane < 2) {
        acc[0] += bflo(sv.x); acc[1] += bfhi(sv.x);
        acc[2] += bflo(sv.y); acc[3] += bfhi(sv.y);
        acc[4] += bflo(sv.z); acc[5] += bfhi(sv.z);
        acc[6] += bflo(sv.w); acc[7] += bfhi(sv.w);
    }
    for (unsigned e0 = start; e0 < end; e0 += 32) {
        unsigned idx = e0 + (unsigned)slot;
        if (idx < end) {
            int s = csr_src[idx];
            uint4 rv = *(const uint4*)(h1p + (size_t)s * 16 + half * 8);
            acc[0] += bflo(rv.x); acc[1] += bfhi(rv.x);
            acc[2] += bflo(rv.y); acc[3] += bfhi(rv.y);
            acc[4] += bflo(rv.z); acc[5] += bfhi(rv.z);
            acc[6] += bflo(rv.w); acc[7] += bfhi(rv.w);
        }
    }
    #pragma unroll
    for (int mk = 2; mk <= 32; mk <<= 1) {
        #pragma unroll
        for (int k = 0; k < 8; ++k) acc[k] += __shfl_xor(acc[k], mk);
    }
    float oth[8];
    #pragma unroll
    for (int k = 0; k < 8; ++k) oth[k] = __shfl_xor(acc[k], 1);

    float di = dinv[node];
    float h[16];
    #pragma unroll
    for (int k = 0; k < 8; ++k) {
        float glo = half ? oth[k] : acc[k];     // feats k
        float ghi = half ? acc[k] : oth[k];     // feats 8+k
        h[k]     = fmaxf(fmaf(di, glo, b1s[k]),     0.f);
        h[k + 8] = fmaxf(fmaf(di, ghi, b1s[k + 8]), 0.f);
    }
    int c = lane & 7;
    float o = 0.f;
    #pragma unroll
    for (int j = 0; j < 16; ++j) o = fmaf(h[j], w2s[j][c], o);
    if (lane < 8)
        h2p[(size_t)node * 8 + c] = (c < N_CLASSES) ? di * o : 0.f;
}

// ------- gather layer 2 + bias + log_softmax fused, wide loads -------------
__global__ __launch_bounds__(256) void k_gather2(const int* __restrict__ csr_src,
                                                 const unsigned* __restrict__ row_start,
                                                 const unsigned* __restrict__ deg,
                                                 const float* __restrict__ dinv,
                                                 const float* __restrict__ h2p,
                                                 const float* __restrict__ b2,
                                                 float* __restrict__ out) {
    int tid  = threadIdx.x;
    int lane = tid & 63;
    int node = blockIdx.x * 4 + (tid >> 6);
    int half = lane & 1;
    int slot = lane >> 1;

    unsigned start = row_start[node];
    unsigned end   = start + deg[node];

    float acc[4] = {0, 0, 0, 0};
    f32x4 sv = *(const f32x4*)(h2p + (size_t)node * 8 + half * 4);
    if (lane < 2) { acc[0] += sv[0]; acc[1] += sv[1]; acc[2] += sv[2]; acc[3] += sv[3]; }
    for (unsigned e0 = start; e0 < end; e0 += 32) {
        unsigned idx = e0 + (unsigned)slot;
        if (idx < end) {
            int s = csr_src[idx];
            f32x4 rv = *(const f32x4*)(h2p + (size_t)s * 8 + half * 4);
            acc[0] += rv[0]; acc[1] += rv[1]; acc[2] += rv[2]; acc[3] += rv[3];
        }
    }
    #pragma unroll
    for (int mk = 2; mk <= 32; mk <<= 1) {
        #pragma unroll
        for (int k = 0; k < 4; ++k) acc[k] += __shfl_xor(acc[k], mk);
    }
    float oth[4];
    #pragma unroll
    for (int k = 0; k < 4; ++k) oth[k] = __shfl_xor(acc[k], 1);

    float l[8];
    #pragma unroll
    for (int k = 0; k < 4; ++k) {
        l[k]     = half ? oth[k] : acc[k];      // classes 0..3
        l[k + 4] = half ? acc[k] : oth[k];      // classes 4..7
    }
    float di = dinv[node];
    float lg[N_CLASSES];
    float mx = -1e30f;
    #pragma unroll
    for (int cc = 0; cc < N_CLASSES; ++cc) {
        lg[cc] = fmaf(di, l[cc], b2[cc]);
        mx = fmaxf(mx, lg[cc]);
    }
    float sum = 0.f;
    #pragma unroll
    for (int cc = 0; cc < N_CLASSES; ++cc) sum += __expf(lg[cc] - mx);
    float lse = mx + __logf(sum);
    if (lane < N_CLASSES) {
        float v = lg[0];
        #pragma unroll
        for (int cc = 1; cc < N_CLASSES; ++cc) if (lane == cc) v = lg[cc];
        out[(size_t)node * N_CLASSES + lane] = v - lse;
    }
}

extern "C" void kernel_launch(void* const* d_in, const int* in_sizes, int n_in,
                              void* d_out, int out_size, void* d_ws, size_t ws_size,
                              hipStream_t stream) {
    const float* x  = (const float*)d_in[0];
    const int*   ei = (const int*)d_in[1];
    const float* w1 = (const float*)d_in[2];
    const float* b1 = (const float*)d_in[3];
    const float* w2 = (const float*)d_in[4];
    const float* b2 = (const float*)d_in[5];
    float* out = (float*)d_out;

    const int* src = ei;
    const int* dst = ei + N_EDGES;

    // workspace carve (u32 units), ~46 MB
    unsigned* w32            = (unsigned*)d_ws;
    float*    dinv           = (float*)(w32 + 0);                   // 102,400
    unsigned short* h1p      = (unsigned short*)(w32 + 102400);     // 1.6M ushort = 800,000 u32
    float*    h2p            = (float*)(w32 + 902400);              //   800,000
    unsigned* deg            = w32 + 1702400;                       // 102,400
    unsigned* row_start      = w32 + 1804800;                       // 102,400
    unsigned* cnt            = w32 + 1907200;                       // 2,048
    float*    graw           = (float*)(w32 + 1909248);             // 1,600,000
    unsigned* packed         = w32 + 3509248;                       // 4,001,280 (NBKT*BCAP)
    int*      csr_src        = (int*)(w32 + 7510528);               // 4,001,280

    hipMemsetAsync(cnt, 0, NBKT * sizeof(unsigned), stream);
    k_fused1 <<<SBLK + GEMMB, 1024, 0, stream>>>(src, dst, cnt, packed, x, w1, graw);
    k_bucket <<<NBKT,  256, 0, stream>>>(packed, cnt, graw, deg, row_start, dinv, csr_src, h1p);
    k_gather1<<<25000, 256, 0, stream>>>(csr_src, row_start, deg, h1p, dinv, w2, b1, h2p);
    k_gather2<<<25000, 256, 0, stream>>>(csr_src, row_start, deg, dinv, h2p, b2, out);
}